// Round 11
// baseline (4051.782 us; speedup 1.0000x reference)
//
#include <hip/hip_runtime.h>
#include <cstdio>
#include <cstdint>

#define TT    20
#define BATCH 512
#define HID   1024
#define G4    4096
#define NG    8192          // both directions' gates, merged per stream
#define BT    (BATCH * TT)  // 10240
#define NCLS  200
#define SH    ((size_t)BATCH * HID)

typedef unsigned short u16;
typedef __attribute__((ext_vector_type(8))) short short8;   // 8 bf16 (4 VGPRs)
typedef __attribute__((ext_vector_type(4))) float f32x4;

__device__ __forceinline__ float sigf(float x) { return 1.0f / (1.0f + __expf(-x)); }

__device__ __forceinline__ u16 f2bf(float x) {
    unsigned u = __float_as_uint(x);
    u += 0x7FFFu + ((u >> 16) & 1u);           // RNE
    return (u16)(u >> 16);
}
__device__ __forceinline__ float bf2f(u16 b) { return __uint_as_float(((unsigned)b) << 16); }

// async 16B global -> LDS; LDS dest must be linear in lane order
__device__ __forceinline__ void gld16(const u16* g, u16* l) {
    __builtin_amdgcn_global_load_lds(
        (const __attribute__((address_space(1))) void*)g,
        (__attribute__((address_space(3))) void*)l, 16, 0, 0);
}

// vectorized fp32 -> plain bf16 convert
__global__ void cvt4_kernel(const float* __restrict__ x, u16* __restrict__ y, int n4)
{
    const int stride = gridDim.x * blockDim.x;
    for (int i = blockIdx.x * blockDim.x + threadIdx.x; i < n4; i += stride) {
        const float4 v = ((const float4*)x)[i];
        uint2 hp;
        hp.x = (unsigned)f2bf(v.x) | ((unsigned)f2bf(v.y) << 16);
        hp.y = (unsigned)f2bf(v.z) | ((unsigned)f2bf(v.w) << 16);
        ((uint2*)y)[i] = hp;
    }
}

// bcat[0:4096] = bih0+bhh0 ; bcat[4096:8192] = bih1+bhh1
__global__ void bias_cat_kernel(const float* __restrict__ bi0, const float* __restrict__ bh0,
                                const float* __restrict__ bi1, const float* __restrict__ bh1,
                                float* __restrict__ bcat)
{
    const int n = blockIdx.x * blockDim.x + threadIdx.x;
    if (n >= NG) return;
    bcat[n] = (n < G4) ? (bi0[n] + bh0[n]) : (bi1[n - G4] + bh1[n - G4]);
}

// ---------------------------------------------------------------------------
// Pure-bf16 MFMA GEMM (m97 structure): C = A[M,K]bf16 @ W[N,K]bf16^T + b.
// Output bf16; NT=true uses non-temporal stores (G path: consumed later,
// keep out of caches). 128x128, BK=32, 4 waves, global_load_lds staging.
// 1D grid, bijective XCD swizzle + chunked supertile (cm m-tiles x all n).
// Requires (M/128) % cm == 0, nwg % 8 == 0, K % 32 == 0.
// ---------------------------------------------------------------------------
template<bool NT>
__launch_bounds__(256)
__global__ void gemm_b16(const u16* __restrict__ A, const u16* __restrict__ W,
                         const float* __restrict__ b1, u16* __restrict__ Cb,
                         int M, int N, int K, int cm)
{
    __shared__ u16 sA[4][128][8]; __shared__ u16 sW[4][128][8];
    const int tid = threadIdx.x, lane = tid & 63, w = tid >> 6;
    const int wr = w >> 1, wc = w & 1;

    const int nwg = gridDim.x;
    const int cpx = nwg >> 3;
    const int lg = (blockIdx.x & 7) * cpx + (blockIdx.x >> 3);
    const int nby = N >> 7;
    const int cb = cm * nby;
    const int chunk = lg / cb;
    const int r = lg - chunk * cb;
    const int m0 = (chunk * cm + (r % cm)) * 128;
    const int n0 = (r / cm) * 128;

    const u16* A0 = A + (size_t)m0 * K;
    const u16* W0 = W + (size_t)n0 * K;

    f32x4 acc[4][4];
#pragma unroll
    for (int i = 0; i < 4; ++i)
#pragma unroll
        for (int j = 0; j < 4; ++j) acc[i][j] = f32x4{0.f, 0.f, 0.f, 0.f};

    const int u1 = tid, u2 = tid + 256;
    const size_t go1 = (size_t)(u1 & 127) * K + (u1 >> 7) * 8;
    const size_t go2 = (size_t)(u2 & 127) * K + (u2 >> 7) * 8;
    u16* const l1 = (u16*)sA + (size_t)u1 * 8;
    u16* const l2 = (u16*)sA + (size_t)u2 * 8;
    const size_t dW = (u16*)sW - (u16*)sA;

    for (int k0 = 0; k0 < K; k0 += 32) {
        gld16(A0 + go1 + k0, l1);       gld16(A0 + go2 + k0, l2);
        gld16(W0 + go1 + k0, l1 + dW);  gld16(W0 + go2 + k0, l2 + dW);
        __syncthreads();

        const int kb = lane >> 4, rr = lane & 15;
        short8 Av[4], Wv[4];
#pragma unroll
        for (int i = 0; i < 4; ++i) {
            Av[i] = *(const short8*)&sA[kb][wr * 64 + i * 16 + rr][0];
            Wv[i] = *(const short8*)&sW[kb][wc * 64 + i * 16 + rr][0];
        }
#pragma unroll
        for (int i = 0; i < 4; ++i)
#pragma unroll
            for (int j = 0; j < 4; ++j)
                acc[i][j] = __builtin_amdgcn_mfma_f32_16x16x32_bf16(Av[i], Wv[j], acc[i][j], 0, 0, 0);
        __syncthreads();
    }

    const int rr = lane & 15, rg = lane >> 4;
#pragma unroll
    for (int j = 0; j < 4; ++j) {
        const int col = n0 + wc * 64 + j * 16 + rr;
        const float bias = b1 ? b1[col] : 0.f;
#pragma unroll
        for (int i = 0; i < 4; ++i) {
#pragma unroll
            for (int q = 0; q < 4; ++q) {
                const int row = m0 + wr * 64 + i * 16 + rg * 4 + q;
                const u16 v = f2bf(acc[i][j][q] + bias);
                if (NT) __builtin_nontemporal_store(v, &Cb[(size_t)row * N + col]);
                else    Cb[(size_t)row * N + col] = v;
            }
        }
    }
}

// ---------------------------------------------------------------------------
// Merged 6-LSTM step: gates = h_in @ Whh^T + G(bf16), then cell update.
// gridDim.z = 6 (all streams, both dirs) -> 1536 blocks = 6/CU.
// Block: 256 threads = 4 waves, tile 64 batch x (32 j x 4 gates).
// Double-buffered K-loop; W gate-interleaved via per-lane global source
// addresses (LDS stays linear). Lane owns all 4 gates of its (b, j).
// ---------------------------------------------------------------------------
__launch_bounds__(256)
__global__ void lstm_step6(const u16* __restrict__ whhAll,   // [6][4096][1024] bf16
                           const u16* __restrict__ Gall,     // [3][BT][8192] bf16
                           const u16* __restrict__ hinAll,   // [6][512][1024] bf16
                           u16* __restrict__ houtAll,
                           float* __restrict__ cbAll,        // [6][512][1024] f32
                           float* __restrict__ hfinAll,      // [6][512][1024] f32
                           int s, int write_hfin)
{
    const int l = blockIdx.z;
    __shared__ u16 sA[2][4][64][8];    // 2 x 4 KB
    __shared__ u16 sW[2][4][128][8];   // 2 x 8 KB
    const int tid = threadIdx.x, lane = tid & 63, w = tid >> 6;
    const int wr = w >> 1, wc = w & 1;
    const int m0 = blockIdx.x * 64;
    const int j0 = blockIdx.y * 32;

    const u16* __restrict__ hin = hinAll + (size_t)l * SH;
    const u16* __restrict__ Whh = whhAll + (size_t)l * G4 * HID;
    const int do_gemm = (s > 0);

    f32x4 acc[2][4];
#pragma unroll
    for (int i = 0; i < 2; ++i)
#pragma unroll
        for (int g = 0; g < 4; ++g) acc[i][g] = f32x4{0.f, 0.f, 0.f, 0.f};

    const int rr = lane & 15, rg = lane >> 4;

    if (do_gemm) {
        // A: 64 rows x 32 k; thread covers row tid&63, chunk tid>>6
        const size_t goA = (size_t)(m0 + (tid & 63)) * HID + (tid >> 6) * 8;
        // W: 128 gate-interleaved rows x 32 k; two gld16 per thread
        const int rW = tid & 127;
        const int wrow = ((rW >> 4) & 3) * HID + j0 + (rW >> 6) * 16 + (rW & 15);
        const size_t goW1 = (size_t)wrow * HID + (tid >> 7) * 8;        // chunks 0-1
        const size_t goW2 = (size_t)wrow * HID + ((tid >> 7) + 2) * 8;  // chunks 2-3
        u16* const ldA  = (u16*)sA + (size_t)tid * 8;
        u16* const ldW1 = (u16*)sW + (size_t)tid * 8;
        u16* const ldW2 = (u16*)sW + (size_t)(tid + 256) * 8;

        gld16(hin + goA,  ldA);
        gld16(Whh + goW1, ldW1);
        gld16(Whh + goW2, ldW2);
        __syncthreads();

        for (int k0 = 0; k0 < HID; k0 += 32) {
            const int bf = (k0 >> 5) & 1;
            if (k0 + 32 < HID) {
                gld16(hin + goA  + k0 + 32, ldA  + (bf ^ 1) * 2048);
                gld16(Whh + goW1 + k0 + 32, ldW1 + (bf ^ 1) * 4096);
                gld16(Whh + goW2 + k0 + 32, ldW2 + (bf ^ 1) * 4096);
            }
            const int kb = lane >> 4;
            short8 Av[2], Wv[4];
#pragma unroll
            for (int i = 0; i < 2; ++i)
                Av[i] = *(const short8*)&sA[bf][kb][wr * 32 + i * 16 + rr][0];
#pragma unroll
            for (int g = 0; g < 4; ++g)
                Wv[g] = *(const short8*)&sW[bf][kb][wc * 64 + g * 16 + rr][0];
#pragma unroll
            for (int i = 0; i < 2; ++i)
#pragma unroll
                for (int g = 0; g < 4; ++g)
                    acc[i][g] = __builtin_amdgcn_mfma_f32_16x16x32_bf16(Av[i], Wv[g], acc[i][g], 0, 0, 0);
            __syncthreads();
        }
    }

    const int j = j0 + wc * 16 + rr;
    const int t = (l & 1) ? (TT - 1 - s) : s;
    const u16* __restrict__ Gl = Gall + (size_t)(l >> 1) * BT * NG + (size_t)(l & 1) * G4;
    float* __restrict__ cb = cbAll + (size_t)l * SH;
    float* __restrict__ hf = hfinAll + (size_t)l * SH;
    u16* __restrict__ ho = houtAll + (size_t)l * SH;
#pragma unroll
    for (int i = 0; i < 2; ++i) {
#pragma unroll
        for (int q = 0; q < 4; ++q) {
            const int b = m0 + wr * 32 + i * 16 + rg * 4 + q;
            const u16* gp = Gl + ((size_t)b * TT + t) * NG + j;
            const float pi = acc[i][0][q] + bf2f(gp[0]);
            const float pf = acc[i][1][q] + bf2f(gp[1024]);
            const float pg = acc[i][2][q] + bf2f(gp[2048]);
            const float po = acc[i][3][q] + bf2f(gp[3072]);
            const size_t idx = (size_t)b * HID + j;
            const float cprev = do_gemm ? cb[idx] : 0.f;
            const float cn = sigf(pf) * cprev + sigf(pi) * tanhf(pg);
            cb[idx] = cn;
            const float h = sigf(po) * tanhf(cn);
            if (write_hfin) hf[idx] = h;
            else            ho[idx] = f2bf(h);
        }
    }
}

// fused[b, n] = prod over streams of concat(h_fwd, h_rev); hfin layout [l][b][j]
__global__ void fuse_mul_kernel(const float* __restrict__ hfin, float* __restrict__ fused)
{
    const int idx = blockIdx.x * blockDim.x + threadIdx.x;
    if (idx >= BATCH * 2 * HID) return;
    const int b = idx >> 11;
    const int n = idx & 2047;
    const int half = n >> 10;
    const int j = n & 1023;
    const size_t o = (size_t)b * HID + j;
    fused[idx] = hfin[(size_t)(0 + half) * SH + o] *
                 hfin[(size_t)(2 + half) * SH + o] *
                 hfin[(size_t)(4 + half) * SH + o];
}

// fp32 vector GEMM for the small classifier (N=200): C = A@W^T + b
__launch_bounds__(256)
__global__ void gemm_bias_kernel(const float* __restrict__ A, const float* __restrict__ W,
                                 const float* __restrict__ b1,
                                 float* __restrict__ C, int M, int N, int K)
{
    __shared__ float As[16][68];
    __shared__ float Ws[16][68];
    const int tid = threadIdx.x;
    const int tx = tid & 15, ty = tid >> 4;
    const int m0 = blockIdx.x * 64;
    const int n0 = blockIdx.y * 64;
    const int lr = tid >> 2;
    const int lk = (tid & 3) << 2;
    const bool mok = (m0 + lr < M);
    const bool nok = (n0 + lr < N);
    const float* Arow = A + (size_t)(m0 + lr) * K + lk;
    const float* Wrow = W + (size_t)(n0 + lr) * K + lk;
    float acc[4][4] = {};

    for (int k0 = 0; k0 < K; k0 += 16) {
        float4 av = make_float4(0.f, 0.f, 0.f, 0.f);
        float4 wv = make_float4(0.f, 0.f, 0.f, 0.f);
        if (mok) av = *(const float4*)(Arow + k0);
        if (nok) wv = *(const float4*)(Wrow + k0);
        As[lk + 0][lr] = av.x; As[lk + 1][lr] = av.y; As[lk + 2][lr] = av.z; As[lk + 3][lr] = av.w;
        Ws[lk + 0][lr] = wv.x; Ws[lk + 1][lr] = wv.y; Ws[lk + 2][lr] = wv.z; Ws[lk + 3][lr] = wv.w;
        __syncthreads();
#pragma unroll
        for (int k = 0; k < 16; ++k) {
            const float4 a = *(const float4*)&As[k][ty << 2];
            const float4 ww = *(const float4*)&Ws[k][tx << 2];
            const float a4[4] = {a.x, a.y, a.z, a.w};
            const float w4[4] = {ww.x, ww.y, ww.z, ww.w};
#pragma unroll
            for (int i = 0; i < 4; ++i)
#pragma unroll
                for (int j = 0; j < 4; ++j)
                    acc[i][j] = fmaf(a4[i], w4[j], acc[i][j]);
        }
        __syncthreads();
    }

#pragma unroll
    for (int i = 0; i < 4; ++i) {
        const int m = m0 + (ty << 2) + i;
        if (m >= M) continue;
#pragma unroll
        for (int j = 0; j < 4; ++j) {
            const int n = n0 + (tx << 2) + j;
            if (n >= N) continue;
            C[(size_t)m * N + n] = acc[i][j] + (b1 ? b1[n] : 0.f);
        }
    }
}

extern "C" void kernel_launch(void* const* d_in, const int* in_sizes, int n_in,
                              void* d_out, int out_size, void* d_ws, size_t ws_size,
                              hipStream_t stream)
{
    const float* resnet   = (const float*)d_in[0];
    const float* c3d      = (const float*)d_in[1];
    const float* audio    = (const float*)d_in[2];
    const float* W_audio  = (const float*)d_in[3];
    const float* b_audio  = (const float*)d_in[4];
    const float* W_resnet = (const float*)d_in[5];
    const float* b_resnet = (const float*)d_in[6];
    const float* W_c3d    = (const float*)d_in[7];
    const float* b_c3d    = (const float*)d_in[8];
    const float* Wih[6]; const float* Whh[6]; const float* bih[6]; const float* bhh[6];
    for (int l = 0; l < 6; ++l) {
        Wih[l] = (const float*)d_in[9 + 4 * l];
        Whh[l] = (const float*)d_in[10 + 4 * l];
        bih[l] = (const float*)d_in[11 + 4 * l];
        bhh[l] = (const float*)d_in[12 + 4 * l];
    }
    const float* W_out = (const float*)d_in[33];
    const float* b_out = (const float*)d_in[34];
    float* out = (float*)d_out;

    const float* feat[3] = { audio, resnet, c3d };
    const float* fw[3]   = { W_audio, W_resnet, W_c3d };
    const float* fb[3]   = { b_audio, b_resnet, b_c3d };
    const int    fK[3]   = { 128, 2048, 4096 };

    // ---- workspace carve (bytes); featB aliased into G[2] (written last) ----
    char* p = (char*)d_ws;
    char* pend = p + ws_size;
    auto alloc = [&](size_t bytes) -> void* {
        void* q = p; p += (bytes + 255) & ~(size_t)255; return q;
    };
    const size_t FW = (size_t)1024 * (128 + 2048 + 4096);
    u16* Gall  = (u16*)alloc((size_t)3 * BT * NG * 2);       // 503 MB, bf16
    u16* featB = Gall + (size_t)2 * BT * NG;                 // alias: inside G[2]
    u16* fwB   = (u16*)alloc(FW * 2);
    u16* wihB  = (u16*)alloc((size_t)NG * HID * 2);          // reused per stream
    u16* whhB  = (u16*)alloc((size_t)3 * NG * HID * 2);      // all 6, [l][4096][1024]
    u16* projB = (u16*)alloc((size_t)BT * HID * 2);
    float* bcat = (float*)alloc((size_t)NG * 4);
    u16* hA    = (u16*)alloc((size_t)6 * SH * 2);
    u16* hB    = (u16*)alloc((size_t)6 * SH * 2);
    float* cb    = (float*)alloc((size_t)6 * SH * 4);
    float* hfin  = (float*)alloc((size_t)6 * SH * 4);
    float* fused = (float*)alloc((size_t)BATCH * 2 * HID * 4);
    if (p > pend) {
        fprintf(stderr, "kernel_launch: ws too small: need %zu have %zu\n",
                (size_t)(p - (char*)d_ws), ws_size);
        return;
    }

    const dim3 blk(256);
    const size_t fwOff[3] = { 0, (size_t)1024 * 128, (size_t)1024 * 128 + (size_t)1024 * 2048 };

    // cvt the three projection weight matrices to bf16 (once)
    for (int st = 0; st < 3; ++st) {
        const int n4 = (1024 * fK[st]) / 4;
        cvt4_kernel<<<dim3(min(2048, (n4 + 255) / 256)), blk, 0, stream>>>(
            fw[st], fwB + fwOff[st], n4);
    }

    // ---- prep all 3 streams: feat cvt -> proj -> weight cvt -> G-GEMM (bf16 NT) ----
    for (int st = 0; st < 3; ++st) {
        const int K = fK[st];
        cvt4_kernel<<<dim3(2048), blk, 0, stream>>>(feat[st], featB, (BT * K) / 4);
        gemm_b16<false><<<dim3((BT / 128) * (HID / 128)), blk, 0, stream>>>(
            featB, fwB + fwOff[st], fb[st], projB, BT, HID, K, 16);
        for (int d = 0; d < 2; ++d) {
            const int l = st * 2 + d;
            cvt4_kernel<<<dim3(2048), blk, 0, stream>>>(
                Wih[l], wihB + (size_t)d * G4 * HID, (G4 * HID) / 4);
            cvt4_kernel<<<dim3(2048), blk, 0, stream>>>(
                Whh[l], whhB + (size_t)l * G4 * HID, (G4 * HID) / 4);
        }
        bias_cat_kernel<<<dim3(NG / 256), blk, 0, stream>>>(
            bih[st * 2], bhh[st * 2], bih[st * 2 + 1], bhh[st * 2 + 1], bcat);
        // writes G[st]; for st==2 this overwrites featB (dead after proj above)
        gemm_b16<true><<<dim3((BT / 128) * (NG / 128)), blk, 0, stream>>>(
            projB, wihB, bcat, Gall + (size_t)st * BT * NG, BT, NG, HID, 40);
    }

    // ---- merged recurrence: 20 launches, all 6 LSTMs per launch ----
    for (int s = 0; s < TT; ++s) {
        const u16* in = (s & 1) ? hB : hA;
        u16*      o  = (s & 1) ? hA : hB;
        lstm_step6<<<dim3(BATCH / 64, HID / 32, 6), blk, 0, stream>>>(
            whhB, Gall, in, o, cb, hfin, s, s == TT - 1 ? 1 : 0);
    }

    // fused elementwise product
    fuse_mul_kernel<<<dim3((BATCH * 2 * HID) / 256), blk, 0, stream>>>(hfin, fused);

    // classifier
    gemm_bias_kernel<<<dim3(BATCH / 64, (NCLS + 63) / 64), blk, 0, stream>>>(
        fused, W_out, b_out, out, BATCH, NCLS, 2 * HID);
}

// Round 13
// 3936.248 us; speedup vs baseline: 1.0294x; 1.0294x over previous
//
#include <hip/hip_runtime.h>
#include <cstdio>
#include <cstdint>

#define TT    20
#define BATCH 512
#define HID   1024
#define G4    4096
#define NG    8192          // both directions' gates, merged per stream
#define BT    (BATCH * TT)  // 10240
#define NCLS  200
#define SH    ((size_t)BATCH * HID)

typedef unsigned short u16;
typedef __attribute__((ext_vector_type(8))) short short8;   // 8 bf16 (4 VGPRs)
typedef __attribute__((ext_vector_type(4))) float f32x4;
typedef __attribute__((ext_vector_type(4))) unsigned int u32x4;  // NT-store-compatible 16B

__device__ __forceinline__ float sigf(float x) { return 1.0f / (1.0f + __expf(-x)); }

__device__ __forceinline__ u16 f2bf(float x) {
    unsigned u = __float_as_uint(x);
    u += 0x7FFFu + ((u >> 16) & 1u);           // RNE
    return (u16)(u >> 16);
}
__device__ __forceinline__ float bf2f(u16 b) { return __uint_as_float(((unsigned)b) << 16); }

// async 16B global -> LDS; LDS dest must be linear in lane order
__device__ __forceinline__ void gld16(const u16* g, u16* l) {
    __builtin_amdgcn_global_load_lds(
        (const __attribute__((address_space(1))) void*)g,
        (__attribute__((address_space(3))) void*)l, 16, 0, 0);
}

// vectorized fp32 -> plain bf16 convert
__global__ void cvt4_kernel(const float* __restrict__ x, u16* __restrict__ y, int n4)
{
    const int stride = gridDim.x * blockDim.x;
    for (int i = blockIdx.x * blockDim.x + threadIdx.x; i < n4; i += stride) {
        const float4 v = ((const float4*)x)[i];
        uint2 hp;
        hp.x = (unsigned)f2bf(v.x) | ((unsigned)f2bf(v.y) << 16);
        hp.y = (unsigned)f2bf(v.z) | ((unsigned)f2bf(v.w) << 16);
        ((uint2*)y)[i] = hp;
    }
}

// bcat[0:4096] = bih0+bhh0 ; bcat[4096:8192] = bih1+bhh1
__global__ void bias_cat_kernel(const float* __restrict__ bi0, const float* __restrict__ bh0,
                                const float* __restrict__ bi1, const float* __restrict__ bh1,
                                float* __restrict__ bcat)
{
    const int n = blockIdx.x * blockDim.x + threadIdx.x;
    if (n >= NG) return;
    bcat[n] = (n < G4) ? (bi0[n] + bh0[n]) : (bi1[n - G4] + bh1[n - G4]);
}

// ---------------------------------------------------------------------------
// Pure-bf16 MFMA GEMM (m97 structure): C = A[M,K]bf16 @ W[N,K]bf16^T + b.
// bf16 output via LDS-repack epilogue -> 64B coalesced stores (NT optional).
// 128x128, BK=32, 4 waves, global_load_lds staging, 16 MFMA/iter.
// 1D grid, bijective XCD swizzle + chunked supertile (cm=8 m-tiles x all n:
// per-XCD concurrent A-footprint ~2MB, fits the 4MB L2).
// Requires (M/128) % cm == 0, nwg % 8 == 0, K % 32 == 0.
// ---------------------------------------------------------------------------
template<bool NT>
__launch_bounds__(256)
__global__ void gemm_b16(const u16* __restrict__ A, const u16* __restrict__ W,
                         const float* __restrict__ b1, u16* __restrict__ Cb,
                         int M, int N, int K, int cm)
{
    __shared__ u16 smem[8192];                          // 16 KB
    u16 (*sA)[128][8] = (u16(*)[128][8])smem;           // [4][128][8] = 8 KB
    u16 (*sW)[128][8] = (u16(*)[128][8])(smem + 4096);  // [4][128][8] = 8 KB
    u16 (*sC)[128]    = (u16(*)[128])smem;              // epilogue: 64x128 bf16

    const int tid = threadIdx.x, lane = tid & 63, w = tid >> 6;
    const int wr = w >> 1, wc = w & 1;

    const int nwg = gridDim.x;
    const int cpx = nwg >> 3;
    const int lg = (blockIdx.x & 7) * cpx + (blockIdx.x >> 3);
    const int nby = N >> 7;
    const int cb = cm * nby;
    const int chunk = lg / cb;
    const int r = lg - chunk * cb;
    const int m0 = (chunk * cm + (r % cm)) * 128;
    const int n0 = (r / cm) * 128;

    const u16* A0 = A + (size_t)m0 * K;
    const u16* W0 = W + (size_t)n0 * K;

    f32x4 acc[4][4];
#pragma unroll
    for (int i = 0; i < 4; ++i)
#pragma unroll
        for (int j = 0; j < 4; ++j) acc[i][j] = f32x4{0.f, 0.f, 0.f, 0.f};

    const int u1 = tid, u2 = tid + 256;
    const size_t go1 = (size_t)(u1 & 127) * K + (u1 >> 7) * 8;
    const size_t go2 = (size_t)(u2 & 127) * K + (u2 >> 7) * 8;
    u16* const l1 = smem + (size_t)u1 * 8;
    u16* const l2 = smem + (size_t)u2 * 8;

    for (int k0 = 0; k0 < K; k0 += 32) {
        gld16(A0 + go1 + k0, l1);         gld16(A0 + go2 + k0, l2);
        gld16(W0 + go1 + k0, l1 + 4096);  gld16(W0 + go2 + k0, l2 + 4096);
        __syncthreads();

        const int kb = lane >> 4, rr = lane & 15;
        short8 Av[4], Wv[4];
#pragma unroll
        for (int i = 0; i < 4; ++i) {
            Av[i] = *(const short8*)&sA[kb][wr * 64 + i * 16 + rr][0];
            Wv[i] = *(const short8*)&sW[kb][wc * 64 + i * 16 + rr][0];
        }
#pragma unroll
        for (int i = 0; i < 4; ++i)
#pragma unroll
            for (int j = 0; j < 4; ++j)
                acc[i][j] = __builtin_amdgcn_mfma_f32_16x16x32_bf16(Av[i], Wv[j], acc[i][j], 0, 0, 0);
        __syncthreads();
    }

    // ---- epilogue: bias + bf16 pack through LDS, 64B coalesced stores ----
    const int rr = lane & 15, rg = lane >> 4;
    float bias[4];
#pragma unroll
    for (int j = 0; j < 4; ++j)
        bias[j] = b1 ? b1[n0 + wc * 64 + j * 16 + rr] : 0.f;

#pragma unroll
    for (int rh = 0; rh < 2; ++rh) {
        if (wr == rh) {
#pragma unroll
            for (int i = 0; i < 4; ++i)
#pragma unroll
                for (int j = 0; j < 4; ++j)
#pragma unroll
                    for (int q = 0; q < 4; ++q)
                        sC[i * 16 + rg * 4 + q][wc * 64 + j * 16 + rr] =
                            f2bf(acc[i][j][q] + bias[j]);
        }
        __syncthreads();
        // 256 threads copy 64 rows x 256B: thread -> row tid>>2, 64B chunk tid&3
        {
            const int row = m0 + rh * 64 + (tid >> 2);
            const u32x4* src = (const u32x4*)&sC[tid >> 2][(tid & 3) * 32];
            u32x4* dst = (u32x4*)&Cb[(size_t)row * N + n0 + (tid & 3) * 32];
#pragma unroll
            for (int k = 0; k < 4; ++k) {
                if (NT) __builtin_nontemporal_store(src[k], &dst[k]);
                else    dst[k] = src[k];
            }
        }
        __syncthreads();
    }
}

// ---------------------------------------------------------------------------
// Merged 6-LSTM step: gates = h_in @ Whh^T + G(bf16), then cell update.
// grid (HID/32, BATCH/64, 6): x = j-tile (fastest) so the 8 m-blocks sharing
// a W-tile are 32 apart in linear id -> same XCD -> W L2-shared.
// Block: 256 threads = 4 waves, tile 64 batch x (32 j x 4 gates).
// Double-buffered K-loop; W gate-interleaved via per-lane global source
// addresses (LDS stays linear). Lane owns all 4 gates of its (b, j).
// ---------------------------------------------------------------------------
__launch_bounds__(256)
__global__ void lstm_step6(const u16* __restrict__ whhAll,   // [6][4096][1024] bf16
                           const u16* __restrict__ Gall,     // [3][BT][8192] bf16
                           const u16* __restrict__ hinAll,   // [6][512][1024] bf16
                           u16* __restrict__ houtAll,
                           float* __restrict__ cbAll,        // [6][512][1024] f32
                           float* __restrict__ hfinAll,      // [6][512][1024] f32
                           int s, int write_hfin)
{
    const int l = blockIdx.z;
    __shared__ u16 sA[2][4][64][8];    // 2 x 4 KB
    __shared__ u16 sW[2][4][128][8];   // 2 x 8 KB
    const int tid = threadIdx.x, lane = tid & 63, w = tid >> 6;
    const int wr = w >> 1, wc = w & 1;
    const int j0 = blockIdx.x * 32;
    const int m0 = blockIdx.y * 64;

    const u16* __restrict__ hin = hinAll + (size_t)l * SH;
    const u16* __restrict__ Whh = whhAll + (size_t)l * G4 * HID;
    const int do_gemm = (s > 0);

    f32x4 acc[2][4];
#pragma unroll
    for (int i = 0; i < 2; ++i)
#pragma unroll
        for (int g = 0; g < 4; ++g) acc[i][g] = f32x4{0.f, 0.f, 0.f, 0.f};

    const int rr = lane & 15, rg = lane >> 4;

    if (do_gemm) {
        // A: 64 rows x 32 k; thread covers row tid&63, chunk tid>>6
        const size_t goA = (size_t)(m0 + (tid & 63)) * HID + (tid >> 6) * 8;
        // W: 128 gate-interleaved rows x 32 k; two gld16 per thread
        const int rW = tid & 127;
        const int wrow = ((rW >> 4) & 3) * HID + j0 + (rW >> 6) * 16 + (rW & 15);
        const size_t goW1 = (size_t)wrow * HID + (tid >> 7) * 8;        // chunks 0-1
        const size_t goW2 = (size_t)wrow * HID + ((tid >> 7) + 2) * 8;  // chunks 2-3
        u16* const ldA  = (u16*)sA + (size_t)tid * 8;
        u16* const ldW1 = (u16*)sW + (size_t)tid * 8;
        u16* const ldW2 = (u16*)sW + (size_t)(tid + 256) * 8;

        gld16(hin + goA,  ldA);
        gld16(Whh + goW1, ldW1);
        gld16(Whh + goW2, ldW2);
        __syncthreads();

        for (int k0 = 0; k0 < HID; k0 += 32) {
            const int bf = (k0 >> 5) & 1;
            if (k0 + 32 < HID) {
                gld16(hin + goA  + k0 + 32, ldA  + (bf ^ 1) * 2048);
                gld16(Whh + goW1 + k0 + 32, ldW1 + (bf ^ 1) * 4096);
                gld16(Whh + goW2 + k0 + 32, ldW2 + (bf ^ 1) * 4096);
            }
            const int kb = lane >> 4;
            short8 Av[2], Wv[4];
#pragma unroll
            for (int i = 0; i < 2; ++i)
                Av[i] = *(const short8*)&sA[bf][kb][wr * 32 + i * 16 + rr][0];
#pragma unroll
            for (int g = 0; g < 4; ++g)
                Wv[g] = *(const short8*)&sW[bf][kb][wc * 64 + g * 16 + rr][0];
#pragma unroll
            for (int i = 0; i < 2; ++i)
#pragma unroll
                for (int g = 0; g < 4; ++g)
                    acc[i][g] = __builtin_amdgcn_mfma_f32_16x16x32_bf16(Av[i], Wv[g], acc[i][g], 0, 0, 0);
            __syncthreads();
        }
    }

    const int j = j0 + wc * 16 + rr;
    const int t = (l & 1) ? (TT - 1 - s) : s;
    const u16* __restrict__ Gl = Gall + (size_t)(l >> 1) * BT * NG + (size_t)(l & 1) * G4;
    float* __restrict__ cb = cbAll + (size_t)l * SH;
    float* __restrict__ hf = hfinAll + (size_t)l * SH;
    u16* __restrict__ ho = houtAll + (size_t)l * SH;
#pragma unroll
    for (int i = 0; i < 2; ++i) {
#pragma unroll
        for (int q = 0; q < 4; ++q) {
            const int b = m0 + wr * 32 + i * 16 + rg * 4 + q;
            const u16* gp = Gl + ((size_t)b * TT + t) * NG + j;
            const float pi = acc[i][0][q] + bf2f(gp[0]);
            const float pf = acc[i][1][q] + bf2f(gp[1024]);
            const float pg = acc[i][2][q] + bf2f(gp[2048]);
            const float po = acc[i][3][q] + bf2f(gp[3072]);
            const size_t idx = (size_t)b * HID + j;
            const float cprev = do_gemm ? cb[idx] : 0.f;
            const float cn = sigf(pf) * cprev + sigf(pi) * tanhf(pg);
            cb[idx] = cn;
            const float h = sigf(po) * tanhf(cn);
            if (write_hfin) hf[idx] = h;
            else            ho[idx] = f2bf(h);
        }
    }
}

// fused[b, n] = prod over streams of concat(h_fwd, h_rev); hfin layout [l][b][j]
__global__ void fuse_mul_kernel(const float* __restrict__ hfin, float* __restrict__ fused)
{
    const int idx = blockIdx.x * blockDim.x + threadIdx.x;
    if (idx >= BATCH * 2 * HID) return;
    const int b = idx >> 11;
    const int n = idx & 2047;
    const int half = n >> 10;
    const int j = n & 1023;
    const size_t o = (size_t)b * HID + j;
    fused[idx] = hfin[(size_t)(0 + half) * SH + o] *
                 hfin[(size_t)(2 + half) * SH + o] *
                 hfin[(size_t)(4 + half) * SH + o];
}

// fp32 vector GEMM for the small classifier (N=200): C = A@W^T + b
__launch_bounds__(256)
__global__ void gemm_bias_kernel(const float* __restrict__ A, const float* __restrict__ W,
                                 const float* __restrict__ b1,
                                 float* __restrict__ C, int M, int N, int K)
{
    __shared__ float As[16][68];
    __shared__ float Ws[16][68];
    const int tid = threadIdx.x;
    const int tx = tid & 15, ty = tid >> 4;
    const int m0 = blockIdx.x * 64;
    const int n0 = blockIdx.y * 64;
    const int lr = tid >> 2;
    const int lk = (tid & 3) << 2;
    const bool mok = (m0 + lr < M);
    const bool nok = (n0 + lr < N);
    const float* Arow = A + (size_t)(m0 + lr) * K + lk;
    const float* Wrow = W + (size_t)(n0 + lr) * K + lk;
    float acc[4][4] = {};

    for (int k0 = 0; k0 < K; k0 += 16) {
        float4 av = make_float4(0.f, 0.f, 0.f, 0.f);
        float4 wv = make_float4(0.f, 0.f, 0.f, 0.f);
        if (mok) av = *(const float4*)(Arow + k0);
        if (nok) wv = *(const float4*)(Wrow + k0);
        As[lk + 0][lr] = av.x; As[lk + 1][lr] = av.y; As[lk + 2][lr] = av.z; As[lk + 3][lr] = av.w;
        Ws[lk + 0][lr] = wv.x; Ws[lk + 1][lr] = wv.y; Ws[lk + 2][lr] = wv.z; Ws[lk + 3][lr] = wv.w;
        __syncthreads();
#pragma unroll
        for (int k = 0; k < 16; ++k) {
            const float4 a = *(const float4*)&As[k][ty << 2];
            const float4 ww = *(const float4*)&Ws[k][tx << 2];
            const float a4[4] = {a.x, a.y, a.z, a.w};
            const float w4[4] = {ww.x, ww.y, ww.z, ww.w};
#pragma unroll
            for (int i = 0; i < 4; ++i)
#pragma unroll
                for (int j = 0; j < 4; ++j)
                    acc[i][j] = fmaf(a4[i], w4[j], acc[i][j]);
        }
        __syncthreads();
    }

#pragma unroll
    for (int i = 0; i < 4; ++i) {
        const int m = m0 + (ty << 2) + i;
        if (m >= M) continue;
#pragma unroll
        for (int j = 0; j < 4; ++j) {
            const int n = n0 + (tx << 2) + j;
            if (n >= N) continue;
            C[(size_t)m * N + n] = acc[i][j] + (b1 ? b1[n] : 0.f);
        }
    }
}

extern "C" void kernel_launch(void* const* d_in, const int* in_sizes, int n_in,
                              void* d_out, int out_size, void* d_ws, size_t ws_size,
                              hipStream_t stream)
{
    const float* resnet   = (const float*)d_in[0];
    const float* c3d      = (const float*)d_in[1];
    const float* audio    = (const float*)d_in[2];
    const float* W_audio  = (const float*)d_in[3];
    const float* b_audio  = (const float*)d_in[4];
    const float* W_resnet = (const float*)d_in[5];
    const float* b_resnet = (const float*)d_in[6];
    const float* W_c3d    = (const float*)d_in[7];
    const float* b_c3d    = (const float*)d_in[8];
    const float* Wih[6]; const float* Whh[6]; const float* bih[6]; const float* bhh[6];
    for (int l = 0; l < 6; ++l) {
        Wih[l] = (const float*)d_in[9 + 4 * l];
        Whh[l] = (const float*)d_in[10 + 4 * l];
        bih[l] = (const float*)d_in[11 + 4 * l];
        bhh[l] = (const float*)d_in[12 + 4 * l];
    }
    const float* W_out = (const float*)d_in[33];
    const float* b_out = (const float*)d_in[34];
    float* out = (float*)d_out;

    const float* feat[3] = { audio, resnet, c3d };
    const float* fw[3]   = { W_audio, W_resnet, W_c3d };
    const float* fb[3]   = { b_audio, b_resnet, b_c3d };
    const int    fK[3]   = { 128, 2048, 4096 };

    // ---- workspace carve (bytes); featB aliased into G[2] (written last) ----
    char* p = (char*)d_ws;
    char* pend = p + ws_size;
    auto alloc = [&](size_t bytes) -> void* {
        void* q = p; p += (bytes + 255) & ~(size_t)255; return q;
    };
    const size_t FW = (size_t)1024 * (128 + 2048 + 4096);
    u16* Gall  = (u16*)alloc((size_t)3 * BT * NG * 2);       // 503 MB, bf16
    u16* featB = Gall + (size_t)2 * BT * NG;                 // alias: inside G[2]
    u16* fwB   = (u16*)alloc(FW * 2);
    u16* wihB  = (u16*)alloc((size_t)NG * HID * 2);          // reused per stream
    u16* whhB  = (u16*)alloc((size_t)3 * NG * HID * 2);      // all 6, [l][4096][1024]
    u16* projB = (u16*)alloc((size_t)BT * HID * 2);
    float* bcat = (float*)alloc((size_t)NG * 4);
    u16* hA    = (u16*)alloc((size_t)6 * SH * 2);
    u16* hB    = (u16*)alloc((size_t)6 * SH * 2);
    float* cb    = (float*)alloc((size_t)6 * SH * 4);
    float* hfin  = (float*)alloc((size_t)6 * SH * 4);
    float* fused = (float*)alloc((size_t)BATCH * 2 * HID * 4);
    if (p > pend) {
        fprintf(stderr, "kernel_launch: ws too small: need %zu have %zu\n",
                (size_t)(p - (char*)d_ws), ws_size);
        return;
    }

    const dim3 blk(256);
    const size_t fwOff[3] = { 0, (size_t)1024 * 128, (size_t)1024 * 128 + (size_t)1024 * 2048 };

    // cvt the three projection weight matrices to bf16 (once)
    for (int st = 0; st < 3; ++st) {
        const int n4 = (1024 * fK[st]) / 4;
        cvt4_kernel<<<dim3(min(2048, (n4 + 255) / 256)), blk, 0, stream>>>(
            fw[st], fwB + fwOff[st], n4);
    }

    // ---- prep all 3 streams: feat cvt -> proj -> weight cvt -> G-GEMM (bf16 NT) ----
    for (int st = 0; st < 3; ++st) {
        const int K = fK[st];
        cvt4_kernel<<<dim3(2048), blk, 0, stream>>>(feat[st], featB, (BT * K) / 4);
        gemm_b16<false><<<dim3((BT / 128) * (HID / 128)), blk, 0, stream>>>(
            featB, fwB + fwOff[st], fb[st], projB, BT, HID, K, 8);
        for (int d = 0; d < 2; ++d) {
            const int l = st * 2 + d;
            cvt4_kernel<<<dim3(2048), blk, 0, stream>>>(
                Wih[l], wihB + (size_t)d * G4 * HID, (G4 * HID) / 4);
            cvt4_kernel<<<dim3(2048), blk, 0, stream>>>(
                Whh[l], whhB + (size_t)l * G4 * HID, (G4 * HID) / 4);
        }
        bias_cat_kernel<<<dim3(NG / 256), blk, 0, stream>>>(
            bih[st * 2], bhh[st * 2], bih[st * 2 + 1], bhh[st * 2 + 1], bcat);
        // writes G[st]; for st==2 this overwrites featB (dead after proj above)
        gemm_b16<true><<<dim3((BT / 128) * (NG / 128)), blk, 0, stream>>>(
            projB, wihB, bcat, Gall + (size_t)st * BT * NG, BT, NG, HID, 8);
    }

    // ---- merged recurrence: 20 launches, all 6 LSTMs per launch ----
    for (int s = 0; s < TT; ++s) {
        const u16* in = (s & 1) ? hB : hA;
        u16*      o  = (s & 1) ? hA : hB;
        lstm_step6<<<dim3(HID / 32, BATCH / 64, 6), blk, 0, stream>>>(
            whhB, Gall, in, o, cb, hfin, s, s == TT - 1 ? 1 : 0);
    }

    // fused elementwise product
    fuse_mul_kernel<<<dim3((BATCH * 2 * HID) / 256), blk, 0, stream>>>(hfin, fused);

    // classifier
    gemm_bias_kernel<<<dim3(BATCH / 64, (NCLS + 63) / 64), blk, 0, stream>>>(
        fused, W_out, b_out, out, BATCH, NCLS, 2 * HID);
}

// Round 14
// 3314.722 us; speedup vs baseline: 1.2224x; 1.1875x over previous
//
#include <hip/hip_runtime.h>
#include <cstdio>
#include <cstdint>

#define TT    20
#define BATCH 512
#define HID   1024
#define G4    4096
#define NG    8192          // both directions' gates, merged per stream
#define BT    (BATCH * TT)  // 10240
#define NCLS  200
#define SH    ((size_t)BATCH * HID)

typedef unsigned short u16;
typedef __attribute__((ext_vector_type(8))) short short8;   // 8 bf16 (4 VGPRs)
typedef __attribute__((ext_vector_type(4))) float f32x4;
typedef __attribute__((ext_vector_type(4))) unsigned short u16x4;  // 8B pack

__device__ __forceinline__ float sigf(float x) { return 1.0f / (1.0f + __expf(-x)); }

__device__ __forceinline__ u16 f2bf(float x) {
    unsigned u = __float_as_uint(x);
    u += 0x7FFFu + ((u >> 16) & 1u);           // RNE
    return (u16)(u >> 16);
}
__device__ __forceinline__ float bf2f(u16 b) { return __uint_as_float(((unsigned)b) << 16); }

// async 16B global -> LDS; LDS dest must be linear in lane order
__device__ __forceinline__ void gld16(const u16* g, u16* l) {
    __builtin_amdgcn_global_load_lds(
        (const __attribute__((address_space(1))) void*)g,
        (__attribute__((address_space(3))) void*)l, 16, 0, 0);
}

// vectorized fp32 -> plain bf16 convert
__global__ void cvt4_kernel(const float* __restrict__ x, u16* __restrict__ y, int n4)
{
    const int stride = gridDim.x * blockDim.x;
    for (int i = blockIdx.x * blockDim.x + threadIdx.x; i < n4; i += stride) {
        const float4 v = ((const float4*)x)[i];
        uint2 hp;
        hp.x = (unsigned)f2bf(v.x) | ((unsigned)f2bf(v.y) << 16);
        hp.y = (unsigned)f2bf(v.z) | ((unsigned)f2bf(v.w) << 16);
        ((uint2*)y)[i] = hp;
    }
}

// bcat[0:4096] = bih0+bhh0 ; bcat[4096:8192] = bih1+bhh1
__global__ void bias_cat_kernel(const float* __restrict__ bi0, const float* __restrict__ bh0,
                                const float* __restrict__ bi1, const float* __restrict__ bh1,
                                float* __restrict__ bcat)
{
    const int n = blockIdx.x * blockDim.x + threadIdx.x;
    if (n >= NG) return;
    bcat[n] = (n < G4) ? (bi0[n] + bh0[n]) : (bi1[n - G4] + bh1[n - G4]);
}

// ---------------------------------------------------------------------------
// Pure-bf16 MFMA GEMM (m97 structure): C = A[M,K]bf16 @ W[N,K]bf16^T + b.
// MODE 0 (proj): plain [M][N] bf16 output, rows PERMUTED b-major -> t-major
//   (row' = (row%20)*512 + row/20), cached scalar stores.
// MODE 1 (G): PACK4 output [M/4][N][4] bf16 (rows already t-major via A),
//   one 8B NT store per (i,j) -> 128B full-line segments, no LDS repack.
// 128x128, BK=32, 4 waves, global_load_lds staging, 16 MFMA/iter.
// 1D grid, bijective XCD swizzle + chunked supertile (cm=8: per-XCD A ~2MB).
// ---------------------------------------------------------------------------
template<int MODE>
__launch_bounds__(256)
__global__ void gemm_b16(const u16* __restrict__ A, const u16* __restrict__ W,
                         const float* __restrict__ b1, u16* __restrict__ Cb,
                         int M, int N, int K, int cm)
{
    __shared__ u16 sA[4][128][8]; __shared__ u16 sW[4][128][8];
    const int tid = threadIdx.x, lane = tid & 63, w = tid >> 6;
    const int wr = w >> 1, wc = w & 1;

    const int nwg = gridDim.x;
    const int cpx = nwg >> 3;
    const int lg = (blockIdx.x & 7) * cpx + (blockIdx.x >> 3);
    const int nby = N >> 7;
    const int cb = cm * nby;
    const int chunk = lg / cb;
    const int r = lg - chunk * cb;
    const int m0 = (chunk * cm + (r % cm)) * 128;
    const int n0 = (r / cm) * 128;

    const u16* A0 = A + (size_t)m0 * K;
    const u16* W0 = W + (size_t)n0 * K;

    f32x4 acc[4][4];
#pragma unroll
    for (int i = 0; i < 4; ++i)
#pragma unroll
        for (int j = 0; j < 4; ++j) acc[i][j] = f32x4{0.f, 0.f, 0.f, 0.f};

    const int u1 = tid, u2 = tid + 256;
    const size_t go1 = (size_t)(u1 & 127) * K + (u1 >> 7) * 8;
    const size_t go2 = (size_t)(u2 & 127) * K + (u2 >> 7) * 8;
    u16* const l1 = (u16*)sA + (size_t)u1 * 8;
    u16* const l2 = (u16*)sA + (size_t)u2 * 8;
    const size_t dW = (u16*)sW - (u16*)sA;

    for (int k0 = 0; k0 < K; k0 += 32) {
        gld16(A0 + go1 + k0, l1);       gld16(A0 + go2 + k0, l2);
        gld16(W0 + go1 + k0, l1 + dW);  gld16(W0 + go2 + k0, l2 + dW);
        __syncthreads();

        const int kb = lane >> 4, rr = lane & 15;
        short8 Av[4], Wv[4];
#pragma unroll
        for (int i = 0; i < 4; ++i) {
            Av[i] = *(const short8*)&sA[kb][wr * 64 + i * 16 + rr][0];
            Wv[i] = *(const short8*)&sW[kb][wc * 64 + i * 16 + rr][0];
        }
#pragma unroll
        for (int i = 0; i < 4; ++i)
#pragma unroll
            for (int j = 0; j < 4; ++j)
                acc[i][j] = __builtin_amdgcn_mfma_f32_16x16x32_bf16(Av[i], Wv[j], acc[i][j], 0, 0, 0);
        __syncthreads();
    }

    const int rr = lane & 15, rg = lane >> 4;
#pragma unroll
    for (int j = 0; j < 4; ++j) {
        const int col = n0 + wc * 64 + j * 16 + rr;
        const float bias = b1 ? b1[col] : 0.f;
#pragma unroll
        for (int i = 0; i < 4; ++i) {
            if (MODE == 1) {
                u16x4 pk;
#pragma unroll
                for (int q = 0; q < 4; ++q) pk[q] = f2bf(acc[i][j][q] + bias);
                const int grp = (m0 >> 2) + wr * 16 + i * 4 + rg;
                __builtin_nontemporal_store(pk, (u16x4*)(Cb + ((size_t)grp * N + col) * 4));
            } else {
#pragma unroll
                for (int q = 0; q < 4; ++q) {
                    const int row = m0 + wr * 64 + i * 16 + rg * 4 + q;
                    const int rowp = (row % 20) * 512 + row / 20;   // b-major -> t-major
                    Cb[(size_t)rowp * N + col] = f2bf(acc[i][j][q] + bias);
                }
            }
        }
    }
}

// ---------------------------------------------------------------------------
// Merged 6-LSTM step: gates = h_in @ Whh^T + G, then cell update.
// G is t-major PACK4: [3][TT][BATCH/4][NG][4] bf16 -> per-step contiguous
// 25MB slice, 8B NT loads (4 q-values per load).
// grid (HID/32, BATCH/64, 6): j fastest -> W-tile consumers share an XCD.
// Block: 256 threads = 4 waves, tile 64 batch x (32 j x 4 gates).
// ---------------------------------------------------------------------------
__launch_bounds__(256)
__global__ void lstm_step6(const u16* __restrict__ whhAll,   // [6][4096][1024] bf16
                           const u16* __restrict__ Gall,     // pack4 t-major
                           const u16* __restrict__ hinAll,   // [6][512][1024] bf16
                           u16* __restrict__ houtAll,
                           float* __restrict__ cbAll,        // [6][512][1024] f32
                           float* __restrict__ hfinAll,      // [6][512][1024] f32
                           int s, int write_hfin)
{
    const int l = blockIdx.z;
    __shared__ u16 sA[2][4][64][8];    // 2 x 4 KB
    __shared__ u16 sW[2][4][128][8];   // 2 x 8 KB
    const int tid = threadIdx.x, lane = tid & 63, w = tid >> 6;
    const int wr = w >> 1, wc = w & 1;
    const int j0 = blockIdx.x * 32;
    const int m0 = blockIdx.y * 64;

    const u16* __restrict__ hin = hinAll + (size_t)l * SH;
    const u16* __restrict__ Whh = whhAll + (size_t)l * G4 * HID;
    const int do_gemm = (s > 0);

    f32x4 acc[2][4];
#pragma unroll
    for (int i = 0; i < 2; ++i)
#pragma unroll
        for (int g = 0; g < 4; ++g) acc[i][g] = f32x4{0.f, 0.f, 0.f, 0.f};

    const int rr = lane & 15, rg = lane >> 4;

    if (do_gemm) {
        // A: 64 rows x 32 k; thread covers row tid&63, chunk tid>>6
        const size_t goA = (size_t)(m0 + (tid & 63)) * HID + (tid >> 6) * 8;
        // W: 128 gate-interleaved rows x 32 k; two gld16 per thread
        const int rW = tid & 127;
        const int wrow = ((rW >> 4) & 3) * HID + j0 + (rW >> 6) * 16 + (rW & 15);
        const size_t goW1 = (size_t)wrow * HID + (tid >> 7) * 8;        // chunks 0-1
        const size_t goW2 = (size_t)wrow * HID + ((tid >> 7) + 2) * 8;  // chunks 2-3
        u16* const ldA  = (u16*)sA + (size_t)tid * 8;
        u16* const ldW1 = (u16*)sW + (size_t)tid * 8;
        u16* const ldW2 = (u16*)sW + (size_t)(tid + 256) * 8;

        gld16(hin + goA,  ldA);
        gld16(Whh + goW1, ldW1);
        gld16(Whh + goW2, ldW2);
        __syncthreads();

        for (int k0 = 0; k0 < HID; k0 += 32) {
            const int bf = (k0 >> 5) & 1;
            if (k0 + 32 < HID) {
                gld16(hin + goA  + k0 + 32, ldA  + (bf ^ 1) * 2048);
                gld16(Whh + goW1 + k0 + 32, ldW1 + (bf ^ 1) * 4096);
                gld16(Whh + goW2 + k0 + 32, ldW2 + (bf ^ 1) * 4096);
            }
            const int kb = lane >> 4;
            short8 Av[2], Wv[4];
#pragma unroll
            for (int i = 0; i < 2; ++i)
                Av[i] = *(const short8*)&sA[bf][kb][wr * 32 + i * 16 + rr][0];
#pragma unroll
            for (int g = 0; g < 4; ++g)
                Wv[g] = *(const short8*)&sW[bf][kb][wc * 64 + g * 16 + rr][0];
#pragma unroll
            for (int i = 0; i < 2; ++i)
#pragma unroll
                for (int g = 0; g < 4; ++g)
                    acc[i][g] = __builtin_amdgcn_mfma_f32_16x16x32_bf16(Av[i], Wv[g], acc[i][g], 0, 0, 0);
            __syncthreads();
        }
    }

    const int j = j0 + wc * 16 + rr;
    const int t = (l & 1) ? (TT - 1 - s) : s;
    const u16* __restrict__ Gl = Gall + (size_t)(l >> 1) * BT * NG;   // pack4 stream base
    const int cbase = (l & 1) * G4 + j;
    float* __restrict__ cb = cbAll + (size_t)l * SH;
    float* __restrict__ hf = hfinAll + (size_t)l * SH;
    u16* __restrict__ ho = houtAll + (size_t)l * SH;
#pragma unroll
    for (int i = 0; i < 2; ++i) {
        const int grp = t * 128 + (m0 >> 2) + wr * 8 + i * 4 + rg;
        const u16* gb = Gl + (size_t)grp * NG * 4;
        const u16x4 g0 = __builtin_nontemporal_load((const u16x4*)(gb + (size_t)cbase * 4));
        const u16x4 g1 = __builtin_nontemporal_load((const u16x4*)(gb + (size_t)(cbase + 1024) * 4));
        const u16x4 g2 = __builtin_nontemporal_load((const u16x4*)(gb + (size_t)(cbase + 2048) * 4));
        const u16x4 g3 = __builtin_nontemporal_load((const u16x4*)(gb + (size_t)(cbase + 3072) * 4));
#pragma unroll
        for (int q = 0; q < 4; ++q) {
            const int b = m0 + wr * 32 + i * 16 + rg * 4 + q;
            const float pi = acc[i][0][q] + bf2f(g0[q]);
            const float pf = acc[i][1][q] + bf2f(g1[q]);
            const float pg = acc[i][2][q] + bf2f(g2[q]);
            const float po = acc[i][3][q] + bf2f(g3[q]);
            const size_t idx = (size_t)b * HID + j;
            const float cprev = do_gemm ? cb[idx] : 0.f;
            const float cn = sigf(pf) * cprev + sigf(pi) * tanhf(pg);
            cb[idx] = cn;
            const float h = sigf(po) * tanhf(cn);
            if (write_hfin) hf[idx] = h;
            else            ho[idx] = f2bf(h);
        }
    }
}

// fused[b, n] = prod over streams of concat(h_fwd, h_rev); hfin layout [l][b][j]
__global__ void fuse_mul_kernel(const float* __restrict__ hfin, float* __restrict__ fused)
{
    const int idx = blockIdx.x * blockDim.x + threadIdx.x;
    if (idx >= BATCH * 2 * HID) return;
    const int b = idx >> 11;
    const int n = idx & 2047;
    const int half = n >> 10;
    const int j = n & 1023;
    const size_t o = (size_t)b * HID + j;
    fused[idx] = hfin[(size_t)(0 + half) * SH + o] *
                 hfin[(size_t)(2 + half) * SH + o] *
                 hfin[(size_t)(4 + half) * SH + o];
}

// fp32 vector GEMM for the small classifier (N=200): C = A@W^T + b
__launch_bounds__(256)
__global__ void gemm_bias_kernel(const float* __restrict__ A, const float* __restrict__ W,
                                 const float* __restrict__ b1,
                                 float* __restrict__ C, int M, int N, int K)
{
    __shared__ float As[16][68];
    __shared__ float Ws[16][68];
    const int tid = threadIdx.x;
    const int tx = tid & 15, ty = tid >> 4;
    const int m0 = blockIdx.x * 64;
    const int n0 = blockIdx.y * 64;
    const int lr = tid >> 2;
    const int lk = (tid & 3) << 2;
    const bool mok = (m0 + lr < M);
    const bool nok = (n0 + lr < N);
    const float* Arow = A + (size_t)(m0 + lr) * K + lk;
    const float* Wrow = W + (size_t)(n0 + lr) * K + lk;
    float acc[4][4] = {};

    for (int k0 = 0; k0 < K; k0 += 16) {
        float4 av = make_float4(0.f, 0.f, 0.f, 0.f);
        float4 wv = make_float4(0.f, 0.f, 0.f, 0.f);
        if (mok) av = *(const float4*)(Arow + k0);
        if (nok) wv = *(const float4*)(Wrow + k0);
        As[lk + 0][lr] = av.x; As[lk + 1][lr] = av.y; As[lk + 2][lr] = av.z; As[lk + 3][lr] = av.w;
        Ws[lk + 0][lr] = wv.x; Ws[lk + 1][lr] = wv.y; Ws[lk + 2][lr] = wv.z; Ws[lk + 3][lr] = wv.w;
        __syncthreads();
#pragma unroll
        for (int k = 0; k < 16; ++k) {
            const float4 a = *(const float4*)&As[k][ty << 2];
            const float4 ww = *(const float4*)&Ws[k][tx << 2];
            const float a4[4] = {a.x, a.y, a.z, a.w};
            const float w4[4] = {ww.x, ww.y, ww.z, ww.w};
#pragma unroll
            for (int i = 0; i < 4; ++i)
#pragma unroll
                for (int j = 0; j < 4; ++j)
                    acc[i][j] = fmaf(a4[i], w4[j], acc[i][j]);
        }
        __syncthreads();
    }

#pragma unroll
    for (int i = 0; i < 4; ++i) {
        const int m = m0 + (ty << 2) + i;
        if (m >= M) continue;
#pragma unroll
        for (int j = 0; j < 4; ++j) {
            const int n = n0 + (tx << 2) + j;
            if (n >= N) continue;
            C[(size_t)m * N + n] = acc[i][j] + (b1 ? b1[n] : 0.f);
        }
    }
}

extern "C" void kernel_launch(void* const* d_in, const int* in_sizes, int n_in,
                              void* d_out, int out_size, void* d_ws, size_t ws_size,
                              hipStream_t stream)
{
    const float* resnet   = (const float*)d_in[0];
    const float* c3d      = (const float*)d_in[1];
    const float* audio    = (const float*)d_in[2];
    const float* W_audio  = (const float*)d_in[3];
    const float* b_audio  = (const float*)d_in[4];
    const float* W_resnet = (const float*)d_in[5];
    const float* b_resnet = (const float*)d_in[6];
    const float* W_c3d    = (const float*)d_in[7];
    const float* b_c3d    = (const float*)d_in[8];
    const float* Wih[6]; const float* Whh[6]; const float* bih[6]; const float* bhh[6];
    for (int l = 0; l < 6; ++l) {
        Wih[l] = (const float*)d_in[9 + 4 * l];
        Whh[l] = (const float*)d_in[10 + 4 * l];
        bih[l] = (const float*)d_in[11 + 4 * l];
        bhh[l] = (const float*)d_in[12 + 4 * l];
    }
    const float* W_out = (const float*)d_in[33];
    const float* b_out = (const float*)d_in[34];
    float* out = (float*)d_out;

    const float* feat[3] = { audio, resnet, c3d };
    const float* fw[3]   = { W_audio, W_resnet, W_c3d };
    const float* fb[3]   = { b_audio, b_resnet, b_c3d };
    const int    fK[3]   = { 128, 2048, 4096 };

    // ---- workspace carve (bytes); featB aliased into G[2] (written last) ----
    char* p = (char*)d_ws;
    char* pend = p + ws_size;
    auto alloc = [&](size_t bytes) -> void* {
        void* q = p; p += (bytes + 255) & ~(size_t)255; return q;
    };
    const size_t FW = (size_t)1024 * (128 + 2048 + 4096);
    u16* Gall  = (u16*)alloc((size_t)3 * BT * NG * 2);       // 503 MB, bf16 pack4 t-major
    u16* featB = Gall + (size_t)2 * BT * NG;                 // alias: inside G[2]
    u16* fwB   = (u16*)alloc(FW * 2);
    u16* wihB  = (u16*)alloc((size_t)NG * HID * 2);          // reused per stream
    u16* whhB  = (u16*)alloc((size_t)3 * NG * HID * 2);      // all 6, [l][4096][1024]
    u16* projB = (u16*)alloc((size_t)BT * HID * 2);          // t-major rows
    float* bcat = (float*)alloc((size_t)NG * 4);
    u16* hA    = (u16*)alloc((size_t)6 * SH * 2);
    u16* hB    = (u16*)alloc((size_t)6 * SH * 2);
    float* cb    = (float*)alloc((size_t)6 * SH * 4);
    float* hfin  = (float*)alloc((size_t)6 * SH * 4);
    float* fused = (float*)alloc((size_t)BATCH * 2 * HID * 4);
    if (p > pend) {
        fprintf(stderr, "kernel_launch: ws too small: need %zu have %zu\n",
                (size_t)(p - (char*)d_ws), ws_size);
        return;
    }

    const dim3 blk(256);
    const size_t fwOff[3] = { 0, (size_t)1024 * 128, (size_t)1024 * 128 + (size_t)1024 * 2048 };

    // cvt the three projection weight matrices to bf16 (once)
    for (int st = 0; st < 3; ++st) {
        const int n4 = (1024 * fK[st]) / 4;
        cvt4_kernel<<<dim3(min(2048, (n4 + 255) / 256)), blk, 0, stream>>>(
            fw[st], fwB + fwOff[st], n4);
    }

    // ---- prep all 3 streams: feat cvt -> proj (t-major) -> weight cvt -> G-GEMM ----
    for (int st = 0; st < 3; ++st) {
        const int K = fK[st];
        cvt4_kernel<<<dim3(2048), blk, 0, stream>>>(feat[st], featB, (BT * K) / 4);
        gemm_b16<0><<<dim3((BT / 128) * (HID / 128)), blk, 0, stream>>>(
            featB, fwB + fwOff[st], fb[st], projB, BT, HID, K, 8);
        for (int d = 0; d < 2; ++d) {
            const int l = st * 2 + d;
            cvt4_kernel<<<dim3(2048), blk, 0, stream>>>(
                Wih[l], wihB + (size_t)d * G4 * HID, (G4 * HID) / 4);
            cvt4_kernel<<<dim3(2048), blk, 0, stream>>>(
                Whh[l], whhB + (size_t)l * G4 * HID, (G4 * HID) / 4);
        }
        bias_cat_kernel<<<dim3(NG / 256), blk, 0, stream>>>(
            bih[st * 2], bhh[st * 2], bih[st * 2 + 1], bhh[st * 2 + 1], bcat);
        // writes G[st] (pack4, t-major rows inherited from proj); st==2 overwrites featB (dead)
        gemm_b16<1><<<dim3((BT / 128) * (NG / 128)), blk, 0, stream>>>(
            projB, wihB, bcat, Gall + (size_t)st * BT * NG, BT, NG, HID, 8);
    }

    // ---- merged recurrence: 20 launches, all 6 LSTMs per launch ----
    for (int s = 0; s < TT; ++s) {
        const u16* in = (s & 1) ? hB : hA;
        u16*      o  = (s & 1) ? hA : hB;
        lstm_step6<<<dim3(HID / 32, BATCH / 64, 6), blk, 0, stream>>>(
            whhB, Gall, in, o, cb, hfin, s, s == TT - 1 ? 1 : 0);
    }

    // fused elementwise product
    fuse_mul_kernel<<<dim3((BATCH * 2 * HID) / 256), blk, 0, stream>>>(hfin, fused);

    // classifier
    gemm_bias_kernel<<<dim3(BATCH / 64, (NCLS + 63) / 64), blk, 0, stream>>>(
        fused, W_out, b_out, out, BATCH, NCLS, 2 * HID);
}